// Round 1
// baseline (513.856 us; speedup 1.0000x reference)
//
#include <hip/hip_runtime.h>
#include <cstddef>

#define NN 100000
#define NE 1600000
#define INF 256
#define OUTF 128

// ---------------- degree count ----------------
__global__ __launch_bounds__(256) void k_degrees(const int* __restrict__ src,
                                                 const int* __restrict__ dst,
                                                 int* __restrict__ deg_out,
                                                 int* __restrict__ deg_in) {
  int e = blockIdx.x * 256 + threadIdx.x;
  if (e < NE) {
    atomicAdd(&deg_out[src[e]], 1);
    atomicAdd(&deg_in[dst[e]], 1);
  }
}

// ---------------- norms ----------------
__global__ __launch_bounds__(256) void k_norms(const int* __restrict__ deg_out,
                                               const int* __restrict__ deg_in,
                                               float* __restrict__ ns,
                                               float* __restrict__ nd) {
  int i = blockIdx.x * 256 + threadIdx.x;
  if (i < NN) {
    int doo = deg_out[i]; if (doo < 1) doo = 1;
    int dii = deg_in[i];  if (dii < 1) dii = 1;
    ns[i] = rsqrtf((float)doo);
    nd[i] = rsqrtf((float)dii);
  }
}

// ---------------- scan (exclusive prefix over in_deg -> row_ptr) ----------------
#define SCAN_B 512
#define SCAN_NB ((NN + SCAN_B - 1) / SCAN_B)   // 196

__global__ __launch_bounds__(SCAN_B) void k_scan1(const int* __restrict__ deg,
                                                  int* __restrict__ incl,
                                                  int* __restrict__ partials) {
  __shared__ int lds[SCAN_B];
  int t = threadIdx.x;
  int i = blockIdx.x * SCAN_B + t;
  lds[t] = (i < NN) ? deg[i] : 0;
  __syncthreads();
  for (int off = 1; off < SCAN_B; off <<= 1) {
    int add = (t >= off) ? lds[t - off] : 0;
    __syncthreads();
    lds[t] += add;
    __syncthreads();
  }
  if (i < NN) incl[i] = lds[t];
  if (t == SCAN_B - 1) partials[blockIdx.x] = lds[t];
}

__global__ __launch_bounds__(256) void k_scan2(int* __restrict__ partials) {
  __shared__ int lds[256];
  int t = threadIdx.x;
  lds[t] = (t < SCAN_NB) ? partials[t] : 0;
  __syncthreads();
  for (int off = 1; off < 256; off <<= 1) {
    int add = (t >= off) ? lds[t - off] : 0;
    __syncthreads();
    lds[t] += add;
    __syncthreads();
  }
  if (t < SCAN_NB) partials[t] = (t == 0) ? 0 : lds[t - 1];
}

__global__ __launch_bounds__(SCAN_B) void k_scan3(const int* __restrict__ deg,
                                                  const int* __restrict__ partials,
                                                  int* __restrict__ row_ptr) {
  int i = blockIdx.x * SCAN_B + threadIdx.x;
  if (i < NN) {
    int incl = row_ptr[i] + partials[blockIdx.x];
    row_ptr[i] = incl - deg[i];
    if (i == NN - 1) row_ptr[NN] = incl;  // == NE
  }
}

// ---------------- CSR fill (store src id per slot) ----------------
__global__ __launch_bounds__(256) void k_fill(const int* __restrict__ src,
                                              const int* __restrict__ dst,
                                              const int* __restrict__ row_ptr,
                                              int* __restrict__ counter,
                                              int* __restrict__ edge_src) {
  int e = blockIdx.x * 256 + threadIdx.x;
  if (e < NE) {
    int d = dst[e];
    int p = atomicAdd(&counter[d], 1);
    edge_src[row_ptr[d] + p] = src[e];
  }
}

// ---------------- GEMM: h = (feat * ns) @ W  (fp32, 64x128 tile, BK=16) ----------------
__global__ __launch_bounds__(256) void k_gemm(const float* __restrict__ feat,
                                              const float* __restrict__ Wm,
                                              const float* __restrict__ ns,
                                              float* __restrict__ h) {
  __shared__ float As[16][68];    // [k][m], padded
  __shared__ float Bs[16][OUTF];  // [k][n]
  const int tid = threadIdx.x;
  const int bm = blockIdx.x * 64;
  const int tx = tid & 15;   // cols tx + 16*j
  const int ty = tid >> 4;   // rows ty + 16*i
  const int ar = tid >> 2;   // 0..63 A-load row
  const int ak = (tid & 3) << 2;
  const int br = tid >> 5;   // 0..7 B-load row
  const int bc = (tid & 31) << 2;
  const int arow = bm + ar;
  const bool aval = arow < NN;
  const float anorm = aval ? ns[arow] : 0.0f;
  const float* aptr = feat + (size_t)arow * INF + ak;

  float acc[4][8];
#pragma unroll
  for (int i = 0; i < 4; ++i)
#pragma unroll
    for (int j = 0; j < 8; ++j) acc[i][j] = 0.0f;

  for (int bk = 0; bk < INF; bk += 16) {
    float4 av = make_float4(0.f, 0.f, 0.f, 0.f);
    if (aval) av = *(const float4*)(aptr + bk);
    float4 bv0 = *(const float4*)&Wm[(bk + br) * OUTF + bc];
    float4 bv1 = *(const float4*)&Wm[(bk + br + 8) * OUTF + bc];
    __syncthreads();
    As[ak + 0][ar] = av.x * anorm;
    As[ak + 1][ar] = av.y * anorm;
    As[ak + 2][ar] = av.z * anorm;
    As[ak + 3][ar] = av.w * anorm;
    *(float4*)&Bs[br][bc] = bv0;
    *(float4*)&Bs[br + 8][bc] = bv1;
    __syncthreads();
#pragma unroll
    for (int k = 0; k < 16; ++k) {
      float a[4], bb[8];
#pragma unroll
      for (int i = 0; i < 4; ++i) a[i] = As[k][ty + 16 * i];
#pragma unroll
      for (int j = 0; j < 8; ++j) bb[j] = Bs[k][tx + 16 * j];
#pragma unroll
      for (int i = 0; i < 4; ++i)
#pragma unroll
        for (int j = 0; j < 8; ++j) acc[i][j] += a[i] * bb[j];
    }
  }
#pragma unroll
  for (int i = 0; i < 4; ++i) {
    int r = bm + ty + 16 * i;
    if (r < NN) {
      float* hp = h + (size_t)r * OUTF;
#pragma unroll
      for (int j = 0; j < 8; ++j) hp[tx + 16 * j] = acc[i][j];
    }
  }
}

// ---------------- aggregation: out[n] = (sum_{e: dst=n} h[src[e]]) * nd[n] + b ----------------
__global__ __launch_bounds__(256) void k_aggr(const float2* __restrict__ h2,
                                              const int* __restrict__ row_ptr,
                                              const int* __restrict__ edge_src,
                                              const float* __restrict__ nd,
                                              const float* __restrict__ bias,
                                              float* __restrict__ out) {
  const int wave = threadIdx.x >> 6;
  const int lane = threadIdx.x & 63;
  const int n = blockIdx.x * 4 + wave;
  if (n >= NN) return;
  const int s0 = row_ptr[n];
  const int s1 = row_ptr[n + 1];
  float ax = 0.f, ay = 0.f;
  for (int j = s0; j < s1; ++j) {
    int s = edge_src[j];
    float2 v = h2[(size_t)s * 64 + lane];
    ax += v.x;
    ay += v.y;
  }
  const float scale = nd[n];
  float2 bb = *(const float2*)&bias[lane * 2];
  float* op = out + (size_t)n * OUTF + lane * 2;
  op[0] = ax * scale + bb.x;
  op[1] = ay * scale + bb.y;
}

// ---------------- launch ----------------
extern "C" void kernel_launch(void* const* d_in, const int* in_sizes, int n_in,
                              void* d_out, int out_size, void* d_ws, size_t ws_size,
                              hipStream_t stream) {
  const float* feat = (const float*)d_in[0];
  const int* src = (const int*)d_in[1];
  const int* dst = (const int*)d_in[2];
  const float* Wm = (const float*)d_in[3];
  const float* bias = (const float*)d_in[4];
  float* out = (float*)d_out;

  char* ws = (char*)d_ws;
  // layout (bytes):
  float* h        = (float*)(ws + 0);           // 51,200,000
  float* ns       = (float*)(ws + 51200000);    //    400,000
  float* nd       = (float*)(ws + 51600000);    //    400,000
  int*   deg_out  = (int*)(ws + 52000000);      //    400,000
  int*   deg_in   = (int*)(ws + 52400000);      //    400,000
  int*   counter  = (int*)(ws + 52800000);      //    400,000
  int*   row_ptr  = (int*)(ws + 53200000);      //    400,004
  int*   edge_src = (int*)(ws + 53600256);      //  6,400,000
  int*   partials = (int*)(ws + 60000512);      //        784

  // zero deg_out, deg_in, counter (contiguous 1.2MB)
  hipMemsetAsync(deg_out, 0, 3 * 400000, stream);

  k_degrees<<<(NE + 255) / 256, 256, 0, stream>>>(src, dst, deg_out, deg_in);
  k_norms<<<(NN + 255) / 256, 256, 0, stream>>>(deg_out, deg_in, ns, nd);
  k_scan1<<<SCAN_NB, SCAN_B, 0, stream>>>(deg_in, row_ptr, partials);
  k_scan2<<<1, 256, 0, stream>>>(partials);
  k_scan3<<<SCAN_NB, SCAN_B, 0, stream>>>(deg_in, partials, row_ptr);
  k_fill<<<(NE + 255) / 256, 256, 0, stream>>>(src, dst, row_ptr, counter, edge_src);
  k_gemm<<<(NN + 63) / 64, 256, 0, stream>>>(feat, Wm, ns, h);
  k_aggr<<<(NN + 3) / 4, 256, 0, stream>>>((const float2*)h, row_ptr, edge_src, nd, bias, out);
}

// Round 2
// 342.541 us; speedup vs baseline: 1.5001x; 1.5001x over previous
//
#include <hip/hip_runtime.h>
#include <hip/hip_bf16.h>
#include <cstddef>

#define NN 100000
#define NE 1600000
#define INF 256
#define OUTF 128

typedef __bf16 bf16x8 __attribute__((ext_vector_type(8)));
typedef float f32x4 __attribute__((ext_vector_type(4)));

// ---------------- degree count ----------------
__global__ __launch_bounds__(256) void k_degrees(const int* __restrict__ src,
                                                 const int* __restrict__ dst,
                                                 int* __restrict__ deg_out,
                                                 int* __restrict__ deg_in) {
  int e = blockIdx.x * 256 + threadIdx.x;
  if (e < NE) {
    atomicAdd(&deg_out[src[e]], 1);
    atomicAdd(&deg_in[dst[e]], 1);
  }
}

// ---------------- W transpose + bf16 convert: Wt[n][k] = W[k][n] ----------------
__global__ __launch_bounds__(256) void k_prepW(const float* __restrict__ W,
                                               __bf16* __restrict__ Wt) {
  int i = blockIdx.x * 256 + threadIdx.x;  // 32768 total
  int n = i & 127, k = i >> 7;
  Wt[n * INF + k] = (__bf16)W[k * OUTF + n];
}

// ---------------- scan (exclusive prefix over in_deg -> row_ptr) ----------------
#define SCAN_B 512
#define SCAN_NB ((NN + SCAN_B - 1) / SCAN_B)   // 196

__global__ __launch_bounds__(SCAN_B) void k_scan1(const int* __restrict__ deg,
                                                  int* __restrict__ incl,
                                                  int* __restrict__ partials) {
  __shared__ int lds[SCAN_B];
  int t = threadIdx.x;
  int i = blockIdx.x * SCAN_B + t;
  lds[t] = (i < NN) ? deg[i] : 0;
  __syncthreads();
  for (int off = 1; off < SCAN_B; off <<= 1) {
    int add = (t >= off) ? lds[t - off] : 0;
    __syncthreads();
    lds[t] += add;
    __syncthreads();
  }
  if (i < NN) incl[i] = lds[t];
  if (t == SCAN_B - 1) partials[blockIdx.x] = lds[t];
}

__global__ __launch_bounds__(256) void k_scan2(int* __restrict__ partials) {
  __shared__ int lds[256];
  int t = threadIdx.x;
  lds[t] = (t < SCAN_NB) ? partials[t] : 0;
  __syncthreads();
  for (int off = 1; off < 256; off <<= 1) {
    int add = (t >= off) ? lds[t - off] : 0;
    __syncthreads();
    lds[t] += add;
    __syncthreads();
  }
  if (t < SCAN_NB) partials[t] = (t == 0) ? 0 : lds[t - 1];
}

// scan3 + norms fused
__global__ __launch_bounds__(SCAN_B) void k_scan3(const int* __restrict__ deg_in,
                                                  const int* __restrict__ deg_out,
                                                  const int* __restrict__ partials,
                                                  int* __restrict__ row_ptr,
                                                  float* __restrict__ ns,
                                                  float* __restrict__ nd) {
  int i = blockIdx.x * SCAN_B + threadIdx.x;
  if (i < NN) {
    int incl = row_ptr[i] + partials[blockIdx.x];
    row_ptr[i] = incl - deg_in[i];
    if (i == NN - 1) row_ptr[NN] = incl;  // == NE
    int doo = deg_out[i]; if (doo < 1) doo = 1;
    int dii = deg_in[i];  if (dii < 1) dii = 1;
    ns[i] = rsqrtf((float)doo);
    nd[i] = rsqrtf((float)dii);
  }
}

// ---------------- CSR fill (store src id per slot) ----------------
__global__ __launch_bounds__(256) void k_fill(const int* __restrict__ src,
                                              const int* __restrict__ dst,
                                              const int* __restrict__ row_ptr,
                                              int* __restrict__ counter,
                                              int* __restrict__ edge_src) {
  int e = blockIdx.x * 256 + threadIdx.x;
  if (e < NE) {
    int d = dst[e];
    int p = atomicAdd(&counter[d], 1);
    edge_src[row_ptr[d] + p] = src[e];
  }
}

// ---------------- MFMA GEMM: h = ns ⊙ (feat @ W), bf16 out ----------------
// 128x128 tile, BK=64, 4 waves in 2x2 of 64x64, 16x16x32 bf16 MFMA.
// LDS row-major [row][k] bf16, 8 slots of 16B per row, XOR swizzle slot^=(row&7).
#define BM 128
#define BK 64

__global__ __launch_bounds__(256) void k_gemm(const float* __restrict__ feat,
                                              const __bf16* __restrict__ Wt,
                                              const float* __restrict__ ns,
                                              __bf16* __restrict__ h) {
  __shared__ __attribute__((aligned(16))) ushort lA[BM * BK];   // 16 KB
  __shared__ __attribute__((aligned(16))) ushort lB[OUTF * BK]; // 16 KB
  const int tid = threadIdx.x;
  const int bm = blockIdx.x * BM;
  const int wave = tid >> 6, l = tid & 63;
  const int wm = wave >> 1, wn = wave & 1;
  const int lr = l & 15, lg = l >> 4;

  // staging assignments
  const int ar = tid >> 2;   // A row (plus +64 on pass 1)
  const int aq = tid & 3;    // A k-quarter: 16 floats
  const int bn = tid >> 1;   // B row (n)
  const int bh = tid & 1;    // B k-half: 32 bf16

  f32x4 acc[4][4];
#pragma unroll
  for (int i = 0; i < 4; ++i)
#pragma unroll
    for (int j = 0; j < 4; ++j) acc[i][j] = (f32x4)0.0f;

  for (int bk = 0; bk < INF; bk += BK) {
    if (bk) __syncthreads();
    // ---- stage A (fp32 -> bf16), two row passes ----
#pragma unroll
    for (int pass = 0; pass < 2; ++pass) {
      int r = ar + pass * 64;
      int grow = bm + r;
      float4 f0 = make_float4(0.f, 0.f, 0.f, 0.f), f1 = f0, f2 = f0, f3 = f0;
      if (grow < NN) {
        const float4* p = (const float4*)(feat + (size_t)grow * INF + bk + aq * 16);
        f0 = p[0]; f1 = p[1]; f2 = p[2]; f3 = p[3];
      }
      bf16x8 w0, w1;
      w0[0] = (__bf16)f0.x; w0[1] = (__bf16)f0.y; w0[2] = (__bf16)f0.z; w0[3] = (__bf16)f0.w;
      w0[4] = (__bf16)f1.x; w0[5] = (__bf16)f1.y; w0[6] = (__bf16)f1.z; w0[7] = (__bf16)f1.w;
      w1[0] = (__bf16)f2.x; w1[1] = (__bf16)f2.y; w1[2] = (__bf16)f2.z; w1[3] = (__bf16)f2.w;
      w1[4] = (__bf16)f3.x; w1[5] = (__bf16)f3.y; w1[6] = (__bf16)f3.z; w1[7] = (__bf16)f3.w;
      int rx = r & 7;
      *(bf16x8*)((char*)lA + r * 128 + (((aq * 2) ^ rx) * 16)) = w0;
      *(bf16x8*)((char*)lA + r * 128 + (((aq * 2 + 1) ^ rx) * 16)) = w1;
    }
    // ---- stage B (already bf16, from Wt[n][k]) ----
    {
      const __bf16* p = Wt + (size_t)bn * INF + bk + bh * 32;
      int nx = bn & 7;
#pragma unroll
      for (int j = 0; j < 4; ++j) {
        bf16x8 wv = *(const bf16x8*)(p + j * 8);
        *(bf16x8*)((char*)lB + bn * 128 + (((bh * 4 + j) ^ nx) * 16)) = wv;
      }
    }
    __syncthreads();
    // ---- compute: 2 k-chunks of 32, 4x4 fragments per wave ----
#pragma unroll
    for (int kk = 0; kk < 2; ++kk) {
      bf16x8 af[4], bfv[4];
      int sl = (kk * 4 + lg) ^ (lr & 7);
#pragma unroll
      for (int mf = 0; mf < 4; ++mf)
        af[mf] = *(const bf16x8*)((const char*)lA + (wm * 64 + mf * 16 + lr) * 128 + sl * 16);
#pragma unroll
      for (int nf = 0; nf < 4; ++nf)
        bfv[nf] = *(const bf16x8*)((const char*)lB + (wn * 64 + nf * 16 + lr) * 128 + sl * 16);
#pragma unroll
      for (int mf = 0; mf < 4; ++mf)
#pragma unroll
        for (int nf = 0; nf < 4; ++nf)
          acc[mf][nf] = __builtin_amdgcn_mfma_f32_16x16x32_bf16(af[mf], bfv[nf], acc[mf][nf], 0, 0, 0);
    }
  }
  // ---- epilogue: scale by ns[row], store bf16 ----
#pragma unroll
  for (int mf = 0; mf < 4; ++mf) {
#pragma unroll
    for (int r = 0; r < 4; ++r) {
      int row = bm + wm * 64 + mf * 16 + lg * 4 + r;
      if (row < NN) {
        float s = ns[row];
        __bf16* hp = h + (size_t)row * OUTF + wn * 64 + lr;
#pragma unroll
        for (int nf = 0; nf < 4; ++nf)
          hp[nf * 16] = (__bf16)(acc[mf][nf][r] * s);
      }
    }
  }
}

// ---------------- aggregation: out[n] = (sum h_bf16[src]) * nd[n] + b ----------------
__global__ __launch_bounds__(256) void k_aggr(const uint* __restrict__ h,
                                              const int* __restrict__ row_ptr,
                                              const int* __restrict__ edge_src,
                                              const float* __restrict__ nd,
                                              const float* __restrict__ bias,
                                              float* __restrict__ out) {
  const int wave = threadIdx.x >> 6;
  const int lane = threadIdx.x & 63;
  const int n = blockIdx.x * 4 + wave;
  if (n >= NN) return;
  const int s0 = row_ptr[n];
  const int s1 = row_ptr[n + 1];
  float ax = 0.f, ay = 0.f;
  int j = s0;
  for (; j + 4 <= s1; j += 4) {
    int e0 = edge_src[j], e1 = edge_src[j + 1], e2 = edge_src[j + 2], e3 = edge_src[j + 3];
    uint v0 = h[(size_t)e0 * 64 + lane];
    uint v1 = h[(size_t)e1 * 64 + lane];
    uint v2 = h[(size_t)e2 * 64 + lane];
    uint v3 = h[(size_t)e3 * 64 + lane];
    ax += (__uint_as_float(v0 << 16) + __uint_as_float(v1 << 16)) +
          (__uint_as_float(v2 << 16) + __uint_as_float(v3 << 16));
    ay += (__uint_as_float(v0 & 0xffff0000u) + __uint_as_float(v1 & 0xffff0000u)) +
          (__uint_as_float(v2 & 0xffff0000u) + __uint_as_float(v3 & 0xffff0000u));
  }
  for (; j < s1; ++j) {
    uint v = h[(size_t)edge_src[j] * 64 + lane];
    ax += __uint_as_float(v << 16);
    ay += __uint_as_float(v & 0xffff0000u);
  }
  const float sc = nd[n];
  float2 bb = *(const float2*)&bias[lane * 2];
  float2 o;
  o.x = ax * sc + bb.x;
  o.y = ay * sc + bb.y;
  *(float2*)&out[(size_t)n * OUTF + lane * 2] = o;
}

// ---------------- launch ----------------
extern "C" void kernel_launch(void* const* d_in, const int* in_sizes, int n_in,
                              void* d_out, int out_size, void* d_ws, size_t ws_size,
                              hipStream_t stream) {
  const float* feat = (const float*)d_in[0];
  const int* src = (const int*)d_in[1];
  const int* dst = (const int*)d_in[2];
  const float* Wm = (const float*)d_in[3];
  const float* bias = (const float*)d_in[4];
  float* out = (float*)d_out;

  char* ws = (char*)d_ws;
  // layout (bytes):
  __bf16* h       = (__bf16*)(ws + 0);           // 25,600,000
  __bf16* Wt      = (__bf16*)(ws + 25600000);    //     65,536
  float*  ns      = (float*)(ws + 25665536);     //    400,000
  float*  nd      = (float*)(ws + 26065536);     //    400,000
  int*    deg_out = (int*)(ws + 26465536);       //    400,000
  int*    deg_in  = (int*)(ws + 26865536);       //    400,000
  int*    counter = (int*)(ws + 27265536);       //    400,000
  int*    row_ptr = (int*)(ws + 27665536);       //    400,004
  int*    edge_src= (int*)(ws + 28065792);       //  6,400,000
  int*    partials= (int*)(ws + 34465792);       //        784

  // zero deg_out, deg_in, counter (contiguous 1.2MB)
  hipMemsetAsync(deg_out, 0, 3 * 400000, stream);

  k_degrees<<<(NE + 255) / 256, 256, 0, stream>>>(src, dst, deg_out, deg_in);
  k_prepW<<<128, 256, 0, stream>>>(Wm, Wt);
  k_scan1<<<SCAN_NB, SCAN_B, 0, stream>>>(deg_in, row_ptr, partials);
  k_scan2<<<1, 256, 0, stream>>>(partials);
  k_scan3<<<SCAN_NB, SCAN_B, 0, stream>>>(deg_in, deg_out, partials, row_ptr, ns, nd);
  k_fill<<<(NE + 255) / 256, 256, 0, stream>>>(src, dst, row_ptr, counter, edge_src);
  k_gemm<<<(NN + BM - 1) / BM, 256, 0, stream>>>(feat, Wt, ns, h);
  k_aggr<<<(NN + 3) / 4, 256, 0, stream>>>((const uint*)h, row_ptr, edge_src, nd, bias, out);
}

// Round 3
// 316.584 us; speedup vs baseline: 1.6231x; 1.0820x over previous
//
#include <hip/hip_runtime.h>
#include <hip/hip_bf16.h>
#include <cstddef>

#define NN 100000
#define NE 1600000
#define INF 256
#define OUTF 128
#define MAXD 64
#define OVFCAP 4096

typedef __bf16 bf16x8 __attribute__((ext_vector_type(8)));
typedef float f32x4 __attribute__((ext_vector_type(4)));

__device__ __forceinline__ float bflo(uint v) { return __uint_as_float(v << 16); }
__device__ __forceinline__ float bfhi(uint v) { return __uint_as_float(v & 0xffff0000u); }

// ---------------- W transpose + bf16 convert: Wt[n][k] = W[k][n] ----------------
__global__ __launch_bounds__(256) void k_prepW(const float* __restrict__ W,
                                               __bf16* __restrict__ Wt) {
  int i = blockIdx.x * 256 + threadIdx.x;  // 32768 total
  int n = i & 127, k = i >> 7;
  Wt[n * INF + k] = (__bf16)W[k * OUTF + n];
}

// ---------------- edges: deg_out count + padded CSR fill (one pass) ----------------
__global__ __launch_bounds__(256) void k_edges(const int* __restrict__ src,
                                               const int* __restrict__ dst,
                                               int* __restrict__ deg_out,
                                               int* __restrict__ cnt_in,
                                               int* __restrict__ edge_src,
                                               int* __restrict__ ovf_cnt,
                                               int2* __restrict__ ovf) {
  int e = blockIdx.x * 256 + threadIdx.x;
  if (e >= NE) return;
  int s = src[e], d = dst[e];
  atomicAdd(&deg_out[s], 1);
  int p = atomicAdd(&cnt_in[d], 1);
  if (p < MAXD) {
    edge_src[d * MAXD + p] = s;
  } else {
    int q = atomicAdd(ovf_cnt, 1);
    if (q < OVFCAP) ovf[q] = make_int2(d, s);
  }
}

// ---------------- direct MFMA GEMM (no LDS): h = feat @ W, bf16 out ----------------
// 1 wave = 16 rows x 128 cols. A from global fp32 (converted), B from Wt (L2-hot).
__global__ __launch_bounds__(256, 4) void k_gemm(const float* __restrict__ feat,
                                                 const __bf16* __restrict__ Wt,
                                                 __bf16* __restrict__ h) {
  const int wave = threadIdx.x >> 6, l = threadIdx.x & 63;
  const int row0 = (blockIdx.x * 4 + wave) * 16;
  if (row0 >= NN) return;  // wave-uniform
  const int ar = l & 15;   // A row within strip / B col within 16-group / D col
  const int kg = l >> 4;   // k-group: k = kg*8 .. +7
  const float* ap = feat + (size_t)(row0 + ar) * INF + kg * 8;
  const __bf16* bp = Wt + (size_t)ar * INF + kg * 8;

  f32x4 acc[8];
#pragma unroll
  for (int i = 0; i < 8; ++i) acc[i] = (f32x4)0.0f;

#pragma unroll
  for (int kk = 0; kk < 8; ++kk) {
    float4 fa = *(const float4*)(ap + kk * 32);
    float4 fb = *(const float4*)(ap + kk * 32 + 4);
    bf16x8 a;
    a[0] = (__bf16)fa.x; a[1] = (__bf16)fa.y; a[2] = (__bf16)fa.z; a[3] = (__bf16)fa.w;
    a[4] = (__bf16)fb.x; a[5] = (__bf16)fb.y; a[6] = (__bf16)fb.z; a[7] = (__bf16)fb.w;
#pragma unroll
    for (int nf = 0; nf < 8; ++nf) {
      bf16x8 b = *(const bf16x8*)(bp + (size_t)nf * 16 * INF + kk * 32);
      acc[nf] = __builtin_amdgcn_mfma_f32_16x16x32_bf16(a, b, acc[nf], 0, 0, 0);
    }
  }
  // D: col = nf*16 + (l&15), row = row0 + (l>>4)*4 + r
#pragma unroll
  for (int nf = 0; nf < 8; ++nf) {
#pragma unroll
    for (int r = 0; r < 4; ++r) {
      h[(size_t)(row0 + kg * 4 + r) * OUTF + nf * 16 + ar] = (__bf16)acc[nf][r];
    }
  }
}

// ---------------- aggregation: out[n] = nd[n] * (sum ns[s]*h[s]) + b ----------------
// 1 wave per node; 2 edges per iter (half-wave each, 32 lanes x uint2 = 256B row).
__global__ __launch_bounds__(256) void k_aggr(const uint2* __restrict__ h2,
                                              const int* __restrict__ cnt_in,
                                              const int* __restrict__ deg_out,
                                              const int* __restrict__ edge_src,
                                              const float* __restrict__ bias,
                                              float* __restrict__ out) {
  const int wave = threadIdx.x >> 6;
  const int lane = threadIdx.x & 63;
  const int half = lane >> 5;
  const int c = lane & 31;  // uint2 column (covers bf16 cols 4c..4c+3)
  const int n = blockIdx.x * 4 + wave;
  if (n >= NN) return;
  const int cnt = cnt_in[n];
  const float ndv = rsqrtf((float)(cnt > 1 ? cnt : 1));
  const int m = cnt < MAXD ? cnt : MAXD;
  const int base = n * MAXD;

  float a0 = 0.f, a1 = 0.f, a2 = 0.f, a3 = 0.f;
  for (int j0 = 0; j0 < m; j0 += 32) {
    const int nb = (m - j0) < 32 ? (m - j0) : 32;
    // preload up to 32 edge ids + their src-norms into lanes 0..31 (dup in 32..63)
    int id = 0;
    float nsv = 0.f;
    if (c < nb) {
      id = edge_src[base + j0 + c];
      int dg = deg_out[id];
      nsv = rsqrtf((float)(dg > 1 ? dg : 1));
    }
    for (int j = 0; j < nb; j += 2) {
      const int jj = j + half;
      const int e = __shfl(id, jj);
      const float nse = __shfl(nsv, jj);
      if (jj < nb) {
        uint2 v = h2[(size_t)e * 32 + c];
        a0 += nse * bflo(v.x);
        a1 += nse * bfhi(v.x);
        a2 += nse * bflo(v.y);
        a3 += nse * bfhi(v.y);
      }
    }
  }
  // combine the two halves
  a0 += __shfl_xor(a0, 32);
  a1 += __shfl_xor(a1, 32);
  a2 += __shfl_xor(a2, 32);
  a3 += __shfl_xor(a3, 32);
  if (half == 0) {
    float4 bb = ((const float4*)bias)[c];
    float4 o;
    o.x = a0 * ndv + bb.x;
    o.y = a1 * ndv + bb.y;
    o.z = a2 * ndv + bb.z;
    o.w = a3 * ndv + bb.w;
    ((float4*)(out + (size_t)n * OUTF))[c] = o;
  }
}

// ---------------- overflow fixup (expected empty) ----------------
__global__ __launch_bounds__(128) void k_ovf(const int* __restrict__ ovf_cnt,
                                             const int2* __restrict__ ovf,
                                             const uint* __restrict__ h,
                                             const int* __restrict__ deg_out,
                                             const int* __restrict__ cnt_in,
                                             float* __restrict__ out) {
  int m = *ovf_cnt;
  if (m > OVFCAP) m = OVFCAP;
  const int t = threadIdx.x;  // 128 = one col each
  for (int i = 0; i < m; ++i) {
    int d = ovf[i].x, s = ovf[i].y;
    int cd = cnt_in[d]; if (cd < 1) cd = 1;
    int ds = deg_out[s]; if (ds < 1) ds = 1;
    float sc = rsqrtf((float)cd) * rsqrtf((float)ds);
    uint hv = h[(size_t)s * 64 + (t >> 1)];
    float v = (t & 1) ? bfhi(hv) : bflo(hv);
    out[(size_t)d * OUTF + t] += v * sc;
  }
}

// ---------------- launch ----------------
extern "C" void kernel_launch(void* const* d_in, const int* in_sizes, int n_in,
                              void* d_out, int out_size, void* d_ws, size_t ws_size,
                              hipStream_t stream) {
  const float* feat = (const float*)d_in[0];
  const int* src = (const int*)d_in[1];
  const int* dst = (const int*)d_in[2];
  const float* Wm = (const float*)d_in[3];
  const float* bias = (const float*)d_in[4];
  float* out = (float*)d_out;

  char* ws = (char*)d_ws;
  __bf16* h        = (__bf16*)(ws + 0);            // 25,600,000
  __bf16* Wt       = (__bf16*)(ws + 25600000);     //     65,536
  int*    deg_out  = (int*)(ws + 25665536);        //    400,000
  int*    cnt_in   = (int*)(ws + 26065536);        //    400,000
  int*    ovf_cnt  = (int*)(ws + 26465536);        //         16 (pad)
  int2*   ovf      = (int2*)(ws + 26465552);       //     32,768
  int*    edge_src = (int*)(ws + 26498560);        // 25,600,000

  // zero deg_out + cnt_in + ovf_cnt (contiguous)
  hipMemsetAsync(deg_out, 0, 800016, stream);

  k_prepW<<<128, 256, 0, stream>>>(Wm, Wt);
  k_edges<<<NE / 256, 256, 0, stream>>>(src, dst, deg_out, cnt_in, edge_src, ovf_cnt, ovf);
  k_gemm<<<(NN / 16 + 3) / 4, 256, 0, stream>>>(feat, Wt, h);
  k_aggr<<<NN / 4, 256, 0, stream>>>((const uint2*)h, cnt_in, deg_out, edge_src, bias, out);
  k_ovf<<<1, 128, 0, stream>>>(ovf_cnt, ovf, (const uint*)h, deg_out, cnt_in, out);
}

// Round 4
// 281.637 us; speedup vs baseline: 1.8245x; 1.1241x over previous
//
#include <hip/hip_runtime.h>
#include <hip/hip_bf16.h>
#include <cstddef>

#define NN 100000
#define NE 1600000
#define INF 256
#define OUTF 128
#define NBKT 196      // buckets: node>>9
#define BSH 9
#define P1B 250       // pass-1 blocks
#define EPB 6400      // edges per pass-1 block (NE/P1B)
#define SCL (NBKT * P1B)  // 49000

typedef __bf16 bf16x8 __attribute__((ext_vector_type(8)));
typedef float f32x4 __attribute__((ext_vector_type(4)));

__device__ __forceinline__ float bflo(uint v) { return __uint_as_float(v << 16); }
__device__ __forceinline__ float bfhi(uint v) { return __uint_as_float(v & 0xffff0000u); }

// ---------------- W transpose + bf16 convert: Wt[n][k] = W[k][n] ----------------
__global__ __launch_bounds__(256) void k_prepW(const float* __restrict__ W,
                                               __bf16* __restrict__ Wt) {
  int i = blockIdx.x * 256 + threadIdx.x;  // 32768 total
  int n = i & 127, k = i >> 7;
  Wt[n * INF + k] = (__bf16)W[k * OUTF + n];
}

// ---------------- P1a: per-block bucket histograms (dst and src) ----------------
__global__ __launch_bounds__(256) void k_p1a(const int* __restrict__ src,
                                             const int* __restrict__ dst,
                                             int* __restrict__ ghd,
                                             int* __restrict__ ghs) {
  __shared__ int lhd[NBKT], lhs[NBKT];
  const int t = threadIdx.x;
  if (t < NBKT) { lhd[t] = 0; lhs[t] = 0; }
  __syncthreads();
  const int base = blockIdx.x * EPB;
#pragma unroll
  for (int i = 0; i < EPB / 256; ++i) {
    int e = base + i * 256 + t;
    atomicAdd(&lhd[dst[e] >> BSH], 1);
    atomicAdd(&lhs[src[e] >> BSH], 1);
  }
  __syncthreads();
  if (t < NBKT) {
    ghd[t * P1B + blockIdx.x] = lhd[t];
    ghs[t * P1B + blockIdx.x] = lhs[t];
  }
}

// ---------------- P1b: exclusive scan of ghd (block 0) / ghs (block 1) in place ----------------
__global__ __launch_bounds__(1024) void k_p1b(int* __restrict__ ghd,
                                              int* __restrict__ ghs,
                                              int* __restrict__ row_start) {
  int* a = blockIdx.x ? ghs : ghd;
  __shared__ int sc[1024];
  const int t = threadIdx.x;
  int lo = t * 48; if (lo > SCL) lo = SCL;
  int hi = lo + 48; if (hi > SCL) hi = SCL;
  int s = 0;
  for (int i = lo; i < hi; ++i) s += a[i];
  sc[t] = s;
  __syncthreads();
  for (int off = 1; off < 1024; off <<= 1) {
    int add = (t >= off) ? sc[t - off] : 0;
    __syncthreads();
    sc[t] += add;
    __syncthreads();
  }
  int ex = t ? sc[t - 1] : 0;
  for (int i = lo; i < hi; ++i) { int v = a[i]; a[i] = ex; ex += v; }
  if (blockIdx.x == 0 && t == 0) row_start[NN] = NE;
}

// ---------------- P1c: scatter records into per-(bucket,block) segments (LDS counters only) ----------------
__global__ __launch_bounds__(256) void k_p1c(const int* __restrict__ src,
                                             const int* __restrict__ dst,
                                             const int* __restrict__ ghd,
                                             const int* __restrict__ ghs,
                                             uint* __restrict__ rec_d,
                                             ushort* __restrict__ rec_s) {
  __shared__ int od[NBKT], os[NBKT];
  const int t = threadIdx.x;
  if (t < NBKT) {
    od[t] = ghd[t * P1B + blockIdx.x];
    os[t] = ghs[t * P1B + blockIdx.x];
  }
  __syncthreads();
  const int base = blockIdx.x * EPB;
#pragma unroll
  for (int i = 0; i < EPB / 256; ++i) {
    int e = base + i * 256 + t;
    int s = src[e], d = dst[e];
    int p = atomicAdd(&od[d >> BSH], 1);
    rec_d[p] = ((uint)s << BSH) | (uint)(d & 511);
    int q = atomicAdd(&os[s >> BSH], 1);
    rec_s[q] = (ushort)(s & 511);
  }
}

// ---------------- P2d: per-bucket CSR build (row_start + edge_src), no global atomics ----------------
__global__ __launch_bounds__(256) void k_p2d(const int* __restrict__ ghd,
                                             const uint* __restrict__ rec_d,
                                             int* __restrict__ edge_src,
                                             int* __restrict__ row_start) {
  __shared__ int lh[512];
  __shared__ int sc[256];
  const int k = blockIdx.x, t = threadIdx.x;
  const int base = ghd[k * P1B];
  const int end = (k == NBKT - 1) ? NE : ghd[(k + 1) * P1B];
  lh[t] = 0; lh[t + 256] = 0;
  __syncthreads();
  for (int j = base + t; j < end; j += 256) atomicAdd(&lh[rec_d[j] & 511], 1);
  __syncthreads();
  int a0 = lh[2 * t], a1 = lh[2 * t + 1];
  sc[t] = a0 + a1;
  __syncthreads();
  for (int off = 1; off < 256; off <<= 1) {
    int add = (t >= off) ? sc[t - off] : 0;
    __syncthreads();
    sc[t] += add;
    __syncthreads();
  }
  int ex = t ? sc[t - 1] : 0;
  int e0 = ex, e1 = ex + a0;
  int n0 = k * 512 + 2 * t;
  if (n0 < NN) row_start[n0] = base + e0;
  if (n0 + 1 < NN) row_start[n0 + 1] = base + e1;
  __syncthreads();
  lh[2 * t] = base + e0;
  lh[2 * t + 1] = base + e1;
  __syncthreads();
  for (int j = base + t; j < end; j += 256) {
    uint r = rec_d[j];
    int p = atomicAdd(&lh[r & 511], 1);
    edge_src[p] = (int)(r >> BSH);
  }
}

// ---------------- P2s: per-bucket out-degree histogram -> ns = rsqrt(max(deg,1)) ----------------
__global__ __launch_bounds__(256) void k_p2s(const int* __restrict__ ghs,
                                             const ushort* __restrict__ rec_s,
                                             float* __restrict__ ns) {
  __shared__ int lh[512];
  const int k = blockIdx.x, t = threadIdx.x;
  const int base = ghs[k * P1B];
  const int end = (k == NBKT - 1) ? NE : ghs[(k + 1) * P1B];
  lh[t] = 0; lh[t + 256] = 0;
  __syncthreads();
  for (int j = base + t; j < end; j += 256) atomicAdd(&lh[rec_s[j]], 1);
  __syncthreads();
  int n0 = k * 512 + t, n1 = n0 + 256;
  if (n0 < NN) { int c = lh[t];       ns[n0] = rsqrtf((float)(c > 1 ? c : 1)); }
  if (n1 < NN) { int c = lh[t + 256]; ns[n1] = rsqrtf((float)(c > 1 ? c : 1)); }
}

// ---------------- direct MFMA GEMM (no LDS): h = feat @ W, bf16 out ----------------
__global__ __launch_bounds__(256, 4) void k_gemm(const float* __restrict__ feat,
                                                 const __bf16* __restrict__ Wt,
                                                 __bf16* __restrict__ h) {
  const int wave = threadIdx.x >> 6, l = threadIdx.x & 63;
  const int row0 = (blockIdx.x * 4 + wave) * 16;
  if (row0 >= NN) return;  // wave-uniform
  const int ar = l & 15;
  const int kg = l >> 4;
  const float* ap = feat + (size_t)(row0 + ar) * INF + kg * 8;
  const __bf16* bp = Wt + (size_t)ar * INF + kg * 8;

  f32x4 acc[8];
#pragma unroll
  for (int i = 0; i < 8; ++i) acc[i] = (f32x4)0.0f;

#pragma unroll
  for (int kk = 0; kk < 8; ++kk) {
    float4 fa = *(const float4*)(ap + kk * 32);
    float4 fb = *(const float4*)(ap + kk * 32 + 4);
    bf16x8 a;
    a[0] = (__bf16)fa.x; a[1] = (__bf16)fa.y; a[2] = (__bf16)fa.z; a[3] = (__bf16)fa.w;
    a[4] = (__bf16)fb.x; a[5] = (__bf16)fb.y; a[6] = (__bf16)fb.z; a[7] = (__bf16)fb.w;
#pragma unroll
    for (int nf = 0; nf < 8; ++nf) {
      bf16x8 b = *(const bf16x8*)(bp + (size_t)nf * 16 * INF + kk * 32);
      acc[nf] = __builtin_amdgcn_mfma_f32_16x16x32_bf16(a, b, acc[nf], 0, 0, 0);
    }
  }
#pragma unroll
  for (int nf = 0; nf < 8; ++nf) {
#pragma unroll
    for (int r = 0; r < 4; ++r) {
      h[(size_t)(row0 + kg * 4 + r) * OUTF + nf * 16 + ar] = (__bf16)acc[nf][r];
    }
  }
}

// ---------------- aggregation: out[n] = nd[n] * (sum ns[s]*h[s]) + b ----------------
// quarter-wave per edge: 16 lanes x uint4 = 256B row; 4 edges in flight, unroll 4.
__global__ __launch_bounds__(256) void k_aggr(const uint4* __restrict__ h4,
                                              const int* __restrict__ row_start,
                                              const float* __restrict__ ns,
                                              const int* __restrict__ edge_src,
                                              const float* __restrict__ bias,
                                              float* __restrict__ out) {
  const int wave = threadIdx.x >> 6;
  const int lane = threadIdx.x & 63;
  const int q = lane >> 4;    // quarter 0..3
  const int cl = lane & 15;   // 16B chunk within row
  const int n = blockIdx.x * 4 + wave;  // grid = NN/4 exact
  const int s0 = row_start[n];
  const int s1 = row_start[n + 1];
  const int cnt = s1 - s0;

  float a0 = 0.f, a1 = 0.f, a2 = 0.f, a3 = 0.f, a4 = 0.f, a5 = 0.f, a6 = 0.f, a7 = 0.f;
  for (int j0 = 0; j0 < cnt; j0 += 64) {
    int nb = cnt - j0; if (nb > 64) nb = 64;
    int idv = 0; float nsv = 0.f;
    if (lane < nb) idv = edge_src[s0 + j0 + lane];
    if (lane < nb) nsv = ns[idv];
#pragma unroll 4
    for (int j = 0; j < nb; j += 4) {
      int jj = j + q;
      int e = __shfl(idv, jj);
      float w = __shfl(nsv, jj);
      if (jj < nb) {
        uint4 v = h4[(size_t)e * 16 + cl];
        a0 += w * bflo(v.x); a1 += w * bfhi(v.x);
        a2 += w * bflo(v.y); a3 += w * bfhi(v.y);
        a4 += w * bflo(v.z); a5 += w * bfhi(v.z);
        a6 += w * bflo(v.w); a7 += w * bfhi(v.w);
      }
    }
  }
  // reduce across the 4 quarters (lanes cl, cl+16, cl+32, cl+48)
  a0 += __shfl_xor(a0, 16); a1 += __shfl_xor(a1, 16); a2 += __shfl_xor(a2, 16); a3 += __shfl_xor(a3, 16);
  a4 += __shfl_xor(a4, 16); a5 += __shfl_xor(a5, 16); a6 += __shfl_xor(a6, 16); a7 += __shfl_xor(a7, 16);
  a0 += __shfl_xor(a0, 32); a1 += __shfl_xor(a1, 32); a2 += __shfl_xor(a2, 32); a3 += __shfl_xor(a3, 32);
  a4 += __shfl_xor(a4, 32); a5 += __shfl_xor(a5, 32); a6 += __shfl_xor(a6, 32); a7 += __shfl_xor(a7, 32);

  if (q == 0) {
    float ndv = rsqrtf((float)(cnt > 1 ? cnt : 1));
    const float4* b4 = (const float4*)bias;
    float4 ba = b4[2 * cl], bb = b4[2 * cl + 1];
    float4 o0, o1;
    o0.x = a0 * ndv + ba.x; o0.y = a1 * ndv + ba.y; o0.z = a2 * ndv + ba.z; o0.w = a3 * ndv + ba.w;
    o1.x = a4 * ndv + bb.x; o1.y = a5 * ndv + bb.y; o1.z = a6 * ndv + bb.z; o1.w = a7 * ndv + bb.w;
    float4* op = (float4*)(out + (size_t)n * OUTF);
    op[2 * cl] = o0;
    op[2 * cl + 1] = o1;
  }
}

// ---------------- launch ----------------
extern "C" void kernel_launch(void* const* d_in, const int* in_sizes, int n_in,
                              void* d_out, int out_size, void* d_ws, size_t ws_size,
                              hipStream_t stream) {
  const float* feat = (const float*)d_in[0];
  const int* src = (const int*)d_in[1];
  const int* dst = (const int*)d_in[2];
  const float* Wm = (const float*)d_in[3];
  const float* bias = (const float*)d_in[4];
  float* out = (float*)d_out;

  char* ws = (char*)d_ws;
  __bf16* h        = (__bf16*)(ws + 0);            // 25,600,000
  __bf16* Wt       = (__bf16*)(ws + 25600000);     //     65,536
  int*    ghd      = (int*)(ws + 25665536);        //    196,096
  int*    ghs      = (int*)(ws + 25861632);        //    196,096
  uint*   rec_d    = (uint*)(ws + 26057728);       //  6,400,000
  ushort* rec_s    = (ushort*)(ws + 32457728);     //  3,200,000
  int*    edge_src = (int*)(ws + 35657728);        //  6,400,000
  int*    row_start= (int*)(ws + 42057728);        //    400,016
  float*  ns       = (float*)(ws + 42457744);      //    400,000

  k_prepW<<<128, 256, 0, stream>>>(Wm, Wt);
  k_p1a<<<P1B, 256, 0, stream>>>(src, dst, ghd, ghs);
  k_p1b<<<2, 1024, 0, stream>>>(ghd, ghs, row_start);
  k_p1c<<<P1B, 256, 0, stream>>>(src, dst, ghd, ghs, rec_d, rec_s);
  k_p2d<<<NBKT, 256, 0, stream>>>(ghd, rec_d, edge_src, row_start);
  k_p2s<<<NBKT, 256, 0, stream>>>(ghs, rec_s, ns);
  k_gemm<<<(NN / 16 + 3) / 4, 256, 0, stream>>>(feat, Wt, h);
  k_aggr<<<NN / 4, 256, 0, stream>>>((const uint4*)h, row_start, ns, edge_src, bias, out);
}

// Round 5
// 262.429 us; speedup vs baseline: 1.9581x; 1.0732x over previous
//
#include <hip/hip_runtime.h>
#include <hip/hip_bf16.h>
#include <cstddef>

#define NN 100000
#define NE 1600000
#define INF 256
#define OUTF 128
#define NBKT 196      // buckets: node>>9
#define BSH 9
#define P1B 250       // pass-1 blocks
#define EPB 6400      // edges per pass-1 block (NE/P1B)
#define SCL (NBKT * P1B)  // 49000

typedef __bf16 bf16x8 __attribute__((ext_vector_type(8)));
typedef float f32x4 __attribute__((ext_vector_type(4)));

__device__ __forceinline__ float bflo(uint v) { return __uint_as_float(v << 16); }
__device__ __forceinline__ float bfhi(uint v) { return __uint_as_float(v & 0xffff0000u); }

// ---------------- P1a: per-block bucket histograms (dst and src) + prepW tail blocks ----------------
__global__ __launch_bounds__(256) void k_p1a(const int* __restrict__ src,
                                             const int* __restrict__ dst,
                                             int* __restrict__ ghd,
                                             int* __restrict__ ghs,
                                             const float* __restrict__ W,
                                             __bf16* __restrict__ Wt) {
  if (blockIdx.x >= P1B) {
    // Wt[n][k] = bf16(W[k][n]) : 32768 elements over 128 blocks
    int i = (blockIdx.x - P1B) * 256 + threadIdx.x;
    int n = i & 127, k = i >> 7;
    Wt[n * INF + k] = (__bf16)W[k * OUTF + n];
    return;
  }
  __shared__ int lhd[NBKT], lhs[NBKT];
  const int t = threadIdx.x;
  if (t < NBKT) { lhd[t] = 0; lhs[t] = 0; }
  __syncthreads();
  const int base = blockIdx.x * EPB;
#pragma unroll
  for (int i = 0; i < EPB / 256; ++i) {
    int e = base + i * 256 + t;
    atomicAdd(&lhd[dst[e] >> BSH], 1);
    atomicAdd(&lhs[src[e] >> BSH], 1);
  }
  __syncthreads();
  if (t < NBKT) {
    ghd[t * P1B + blockIdx.x] = lhd[t];
    ghs[t * P1B + blockIdx.x] = lhs[t];
  }
}

// ---------------- P1b: exclusive scan of ghd (block 0) / ghs (block 1) in place ----------------
__global__ __launch_bounds__(1024) void k_p1b(int* __restrict__ ghd,
                                              int* __restrict__ ghs,
                                              int* __restrict__ row_start) {
  int* a = blockIdx.x ? ghs : ghd;
  __shared__ int sc[1024];
  const int t = threadIdx.x;
  int lo = t * 48; if (lo > SCL) lo = SCL;
  int hi = lo + 48; if (hi > SCL) hi = SCL;
  int s = 0;
  for (int i = lo; i < hi; ++i) s += a[i];
  sc[t] = s;
  __syncthreads();
  for (int off = 1; off < 1024; off <<= 1) {
    int add = (t >= off) ? sc[t - off] : 0;
    __syncthreads();
    sc[t] += add;
    __syncthreads();
  }
  int ex = t ? sc[t - 1] : 0;
  for (int i = lo; i < hi; ++i) { int v = a[i]; a[i] = ex; ex += v; }
  if (blockIdx.x == 0 && t == 0) row_start[NN] = NE;
}

// ---------------- P1c: scatter records into per-(bucket,block) segments (LDS counters only) ----------------
__global__ __launch_bounds__(256) void k_p1c(const int* __restrict__ src,
                                             const int* __restrict__ dst,
                                             const int* __restrict__ ghd,
                                             const int* __restrict__ ghs,
                                             uint* __restrict__ rec_d,
                                             ushort* __restrict__ rec_s) {
  __shared__ int od[NBKT], os[NBKT];
  const int t = threadIdx.x;
  if (t < NBKT) {
    od[t] = ghd[t * P1B + blockIdx.x];
    os[t] = ghs[t * P1B + blockIdx.x];
  }
  __syncthreads();
  const int base = blockIdx.x * EPB;
#pragma unroll
  for (int i = 0; i < EPB / 256; ++i) {
    int e = base + i * 256 + t;
    int s = src[e], d = dst[e];
    int p = atomicAdd(&od[d >> BSH], 1);
    rec_d[p] = ((uint)s << BSH) | (uint)(d & 511);
    int q = atomicAdd(&os[s >> BSH], 1);
    rec_s[q] = (ushort)(s & 511);
  }
}

// ---------------- P2: per-bucket CSR build (row_start + edge_src) then out-degree -> ns ----------------
__global__ __launch_bounds__(256) void k_p2(const int* __restrict__ ghd,
                                            const int* __restrict__ ghs,
                                            const uint* __restrict__ rec_d,
                                            const ushort* __restrict__ rec_s,
                                            int* __restrict__ edge_src,
                                            int* __restrict__ row_start,
                                            float* __restrict__ ns) {
  __shared__ int lh[512];
  __shared__ int sc[256];
  const int k = blockIdx.x, t = threadIdx.x;
  // ---- phase 1: dst CSR ----
  {
    const int base = ghd[k * P1B];
    const int end = (k == NBKT - 1) ? NE : ghd[(k + 1) * P1B];
    lh[t] = 0; lh[t + 256] = 0;
    __syncthreads();
    for (int j = base + t; j < end; j += 256) atomicAdd(&lh[rec_d[j] & 511], 1);
    __syncthreads();
    int a0 = lh[2 * t], a1 = lh[2 * t + 1];
    sc[t] = a0 + a1;
    __syncthreads();
    for (int off = 1; off < 256; off <<= 1) {
      int add = (t >= off) ? sc[t - off] : 0;
      __syncthreads();
      sc[t] += add;
      __syncthreads();
    }
    int ex = t ? sc[t - 1] : 0;
    int e0 = ex, e1 = ex + a0;
    int n0 = k * 512 + 2 * t;
    if (n0 < NN) row_start[n0] = base + e0;
    if (n0 + 1 < NN) row_start[n0 + 1] = base + e1;
    __syncthreads();
    lh[2 * t] = base + e0;
    lh[2 * t + 1] = base + e1;
    __syncthreads();
    for (int j = base + t; j < end; j += 256) {
      uint r = rec_d[j];
      int p = atomicAdd(&lh[r & 511], 1);
      edge_src[p] = (int)(r >> BSH);
    }
  }
  __syncthreads();
  // ---- phase 2: src degree -> ns ----
  {
    const int base = ghs[k * P1B];
    const int end = (k == NBKT - 1) ? NE : ghs[(k + 1) * P1B];
    lh[t] = 0; lh[t + 256] = 0;
    __syncthreads();
    for (int j = base + t; j < end; j += 256) atomicAdd(&lh[rec_s[j]], 1);
    __syncthreads();
    int n0 = k * 512 + t, n1 = n0 + 256;
    if (n0 < NN) { int c = lh[t];       ns[n0] = rsqrtf((float)(c > 1 ? c : 1)); }
    if (n1 < NN) { int c = lh[t + 256]; ns[n1] = rsqrtf((float)(c > 1 ? c : 1)); }
  }
}

// ---------------- MFMA GEMM: h = feat @ W (bf16 out), B-in-registers, pipelined A stream ----------------
// Wave = 32 rows x 64 cols. Block = 4 waves = 64 rows x 128 cols.
__global__ __launch_bounds__(256) void k_gemm(const float* __restrict__ feat,
                                              const __bf16* __restrict__ Wt,
                                              __bf16* __restrict__ h) {
  const int w = threadIdx.x >> 6, l = threadIdx.x & 63;
  const int lr = l & 15, lg = l >> 4;
  const int row0 = blockIdx.x * 64 + (w >> 1) * 32;
  const int col0 = (w & 1) * 64;

  // ---- B fragments: 4 nf x 8 kk, loaded once (Wt is L2-hot, 64 KB) ----
  bf16x8 bf[4][8];
  const __bf16* bp = Wt + (size_t)(col0 + lr) * INF + lg * 8;
#pragma unroll
  for (int nf = 0; nf < 4; ++nf)
#pragma unroll
    for (int kk = 0; kk < 8; ++kk)
      bf[nf][kk] = *(const bf16x8*)(bp + (size_t)nf * 16 * INF + kk * 32);

  f32x4 acc[2][4];
#pragma unroll
  for (int i = 0; i < 2; ++i)
#pragma unroll
    for (int j = 0; j < 4; ++j) acc[i][j] = (f32x4)0.0f;

  // ---- A stream: rows mf*16 + lr, k-chunk lg*8, prefetch one kk ahead ----
  int r0 = row0 + lr;      if (r0 >= NN) r0 = NN - 1;
  int r1 = row0 + 16 + lr; if (r1 >= NN) r1 = NN - 1;
  const float* ap0 = feat + (size_t)r0 * INF + lg * 8;
  const float* ap1 = feat + (size_t)r1 * INF + lg * 8;

  float4 c0l = *(const float4*)(ap0);
  float4 c0h = *(const float4*)(ap0 + 4);
  float4 c1l = *(const float4*)(ap1);
  float4 c1h = *(const float4*)(ap1 + 4);

#pragma unroll
  for (int kk = 0; kk < 8; ++kk) {
    float4 n0l, n0h, n1l, n1h;
    if (kk < 7) {
      const float* p0 = ap0 + (kk + 1) * 32;
      const float* p1 = ap1 + (kk + 1) * 32;
      n0l = *(const float4*)(p0);
      n0h = *(const float4*)(p0 + 4);
      n1l = *(const float4*)(p1);
      n1h = *(const float4*)(p1 + 4);
    }
    bf16x8 a0, a1;
    a0[0] = (__bf16)c0l.x; a0[1] = (__bf16)c0l.y; a0[2] = (__bf16)c0l.z; a0[3] = (__bf16)c0l.w;
    a0[4] = (__bf16)c0h.x; a0[5] = (__bf16)c0h.y; a0[6] = (__bf16)c0h.z; a0[7] = (__bf16)c0h.w;
    a1[0] = (__bf16)c1l.x; a1[1] = (__bf16)c1l.y; a1[2] = (__bf16)c1l.z; a1[3] = (__bf16)c1l.w;
    a1[4] = (__bf16)c1h.x; a1[5] = (__bf16)c1h.y; a1[6] = (__bf16)c1h.z; a1[7] = (__bf16)c1h.w;
#pragma unroll
    for (int nf = 0; nf < 4; ++nf) {
      acc[0][nf] = __builtin_amdgcn_mfma_f32_16x16x32_bf16(a0, bf[nf][kk], acc[0][nf], 0, 0, 0);
      acc[1][nf] = __builtin_amdgcn_mfma_f32_16x16x32_bf16(a1, bf[nf][kk], acc[1][nf], 0, 0, 0);
    }
    c0l = n0l; c0h = n0h; c1l = n1l; c1h = n1h;
  }

  // ---- store: row = row0 + mf*16 + lg*4 + r, col = col0 + nf*16 + lr ----
#pragma unroll
  for (int mf = 0; mf < 2; ++mf) {
#pragma unroll
    for (int r = 0; r < 4; ++r) {
      int row = row0 + mf * 16 + lg * 4 + r;
      if (row < NN) {
        __bf16* hp = h + (size_t)row * OUTF + col0 + lr;
#pragma unroll
        for (int nf = 0; nf < 4; ++nf)
          hp[nf * 16] = (__bf16)(acc[mf][nf][r]);
      }
    }
  }
}

// ---------------- aggregation: out[n] = nd[n] * (sum ns[s]*h[s]) + b ----------------
// quarter-wave per edge: 16 lanes x uint4 = 256B row; 4 edges in flight, unroll 4.
__global__ __launch_bounds__(256) void k_aggr(const uint4* __restrict__ h4,
                                              const int* __restrict__ row_start,
                                              const float* __restrict__ ns,
                                              const int* __restrict__ edge_src,
                                              const float* __restrict__ bias,
                                              float* __restrict__ out) {
  const int wave = threadIdx.x >> 6;
  const int lane = threadIdx.x & 63;
  const int q = lane >> 4;    // quarter 0..3
  const int cl = lane & 15;   // 16B chunk within row
  const int n = blockIdx.x * 4 + wave;  // grid = NN/4 exact
  const int s0 = row_start[n];
  const int s1 = row_start[n + 1];
  const int cnt = s1 - s0;

  float a0 = 0.f, a1 = 0.f, a2 = 0.f, a3 = 0.f, a4 = 0.f, a5 = 0.f, a6 = 0.f, a7 = 0.f;
  for (int j0 = 0; j0 < cnt; j0 += 64) {
    int nb = cnt - j0; if (nb > 64) nb = 64;
    int idv = 0; float nsv = 0.f;
    if (lane < nb) idv = edge_src[s0 + j0 + lane];
    if (lane < nb) nsv = ns[idv];
#pragma unroll 4
    for (int j = 0; j < nb; j += 4) {
      int jj = j + q;
      int e = __shfl(idv, jj);
      float w = __shfl(nsv, jj);
      if (jj < nb) {
        uint4 v = h4[(size_t)e * 16 + cl];
        a0 += w * bflo(v.x); a1 += w * bfhi(v.x);
        a2 += w * bflo(v.y); a3 += w * bfhi(v.y);
        a4 += w * bflo(v.z); a5 += w * bfhi(v.z);
        a6 += w * bflo(v.w); a7 += w * bfhi(v.w);
      }
    }
  }
  a0 += __shfl_xor(a0, 16); a1 += __shfl_xor(a1, 16); a2 += __shfl_xor(a2, 16); a3 += __shfl_xor(a3, 16);
  a4 += __shfl_xor(a4, 16); a5 += __shfl_xor(a5, 16); a6 += __shfl_xor(a6, 16); a7 += __shfl_xor(a7, 16);
  a0 += __shfl_xor(a0, 32); a1 += __shfl_xor(a1, 32); a2 += __shfl_xor(a2, 32); a3 += __shfl_xor(a3, 32);
  a4 += __shfl_xor(a4, 32); a5 += __shfl_xor(a5, 32); a6 += __shfl_xor(a6, 32); a7 += __shfl_xor(a7, 32);

  if (q == 0) {
    float ndv = rsqrtf((float)(cnt > 1 ? cnt : 1));
    const float4* b4 = (const float4*)bias;
    float4 ba = b4[2 * cl], bb = b4[2 * cl + 1];
    float4 o0, o1;
    o0.x = a0 * ndv + ba.x; o0.y = a1 * ndv + ba.y; o0.z = a2 * ndv + ba.z; o0.w = a3 * ndv + ba.w;
    o1.x = a4 * ndv + bb.x; o1.y = a5 * ndv + bb.y; o1.z = a6 * ndv + bb.z; o1.w = a7 * ndv + bb.w;
    float4* op = (float4*)(out + (size_t)n * OUTF);
    op[2 * cl] = o0;
    op[2 * cl + 1] = o1;
  }
}

// ---------------- launch ----------------
extern "C" void kernel_launch(void* const* d_in, const int* in_sizes, int n_in,
                              void* d_out, int out_size, void* d_ws, size_t ws_size,
                              hipStream_t stream) {
  const float* feat = (const float*)d_in[0];
  const int* src = (const int*)d_in[1];
  const int* dst = (const int*)d_in[2];
  const float* Wm = (const float*)d_in[3];
  const float* bias = (const float*)d_in[4];
  float* out = (float*)d_out;

  char* ws = (char*)d_ws;
  __bf16* h        = (__bf16*)(ws + 0);            // 25,600,000
  __bf16* Wt       = (__bf16*)(ws + 25600000);     //     65,536
  int*    ghd      = (int*)(ws + 25665536);        //    196,096
  int*    ghs      = (int*)(ws + 25861632);        //    196,096
  uint*   rec_d    = (uint*)(ws + 26057728);       //  6,400,000
  ushort* rec_s    = (ushort*)(ws + 32457728);     //  3,200,000
  int*    edge_src = (int*)(ws + 35657728);        //  6,400,000
  int*    row_start= (int*)(ws + 42057728);        //    400,016
  float*  ns       = (float*)(ws + 42457744);      //    400,000

  k_p1a<<<P1B + 128, 256, 0, stream>>>(src, dst, ghd, ghs, Wm, Wt);
  k_p1b<<<2, 1024, 0, stream>>>(ghd, ghs, row_start);
  k_p1c<<<P1B, 256, 0, stream>>>(src, dst, ghd, ghs, rec_d, rec_s);
  k_p2<<<NBKT, 256, 0, stream>>>(ghd, ghs, rec_d, rec_s, edge_src, row_start, ns);
  k_gemm<<<(NN + 63) / 64, 256, 0, stream>>>(feat, Wt, h);
  k_aggr<<<NN / 4, 256, 0, stream>>>((const uint4*)h, row_start, ns, edge_src, bias, out);
}

// Round 6
// 196.940 us; speedup vs baseline: 2.6092x; 1.3325x over previous
//
#include <hip/hip_runtime.h>
#include <hip/hip_bf16.h>
#include <cstddef>

#define NN 100000
#define NE 1600000
#define INF 256
#define OUTF 128
#define NBKT 196      // buckets: node>>9
#define BSH 9
#define P1B 250       // pass-1 blocks
#define EPB 6400      // edges per pass-1 block (NE/P1B)
#define SCL (NBKT * P1B)  // 49000
#define SCLP 49152    // padded to 1024*48

typedef __bf16 bf16x8 __attribute__((ext_vector_type(8)));
typedef float f32x4 __attribute__((ext_vector_type(4)));

__device__ __forceinline__ float bflo(uint v) { return __uint_as_float(v << 16); }
__device__ __forceinline__ float bfhi(uint v) { return __uint_as_float(v & 0xffff0000u); }

// ---------------- P1a: per-block bucket histograms (dst and src) + prepW/pad tail blocks ----------------
__global__ __launch_bounds__(256) void k_p1a(const int* __restrict__ src,
                                             const int* __restrict__ dst,
                                             int* __restrict__ ghd,
                                             int* __restrict__ ghs,
                                             const float* __restrict__ W,
                                             __bf16* __restrict__ Wt) {
  if (blockIdx.x >= P1B) {
    // Wt[n][k] = bf16(W[k][n]) : 32768 elements over 128 blocks; also zero scan pads
    int i = (blockIdx.x - P1B) * 256 + threadIdx.x;
    if (i < SCLP - SCL) { ghd[SCL + i] = 0; ghs[SCL + i] = 0; }
    int n = i & 127, k = i >> 7;
    Wt[n * INF + k] = (__bf16)W[k * OUTF + n];
    return;
  }
  __shared__ int lhd[NBKT], lhs[NBKT];
  const int t = threadIdx.x;
  if (t < NBKT) { lhd[t] = 0; lhs[t] = 0; }
  __syncthreads();
  const int base = blockIdx.x * EPB;
#pragma unroll
  for (int i = 0; i < EPB / 256; ++i) {
    int e = base + i * 256 + t;
    atomicAdd(&lhd[dst[e] >> BSH], 1);
    atomicAdd(&lhs[src[e] >> BSH], 1);
  }
  __syncthreads();
  if (t < NBKT) {
    ghd[t * P1B + blockIdx.x] = lhd[t];
    ghs[t * P1B + blockIdx.x] = lhs[t];
  }
}

// ---------------- P1b: exclusive scan, vectorized (int4 x12 per thread, shuffle scan) ----------------
__global__ __launch_bounds__(1024) void k_p1b(int* __restrict__ ghd,
                                              int* __restrict__ ghs,
                                              int* __restrict__ row_start) {
  int* a = blockIdx.x ? ghs : ghd;
  __shared__ int wsum[16];
  const int t = threadIdx.x;
  const int lane = t & 63, wid = t >> 6;
  int4 v[12];
  const int4* p = (const int4*)(a + t * 48);
#pragma unroll
  for (int i = 0; i < 12; ++i) v[i] = p[i];
  int s = 0;
#pragma unroll
  for (int i = 0; i < 12; ++i) s += v[i].x + v[i].y + v[i].z + v[i].w;
  const int mysum = s;
  // wave-inclusive scan of per-thread sums
#pragma unroll
  for (int d = 1; d < 64; d <<= 1) {
    int u = __shfl_up(s, d);
    if (lane >= d) s += u;
  }
  if (lane == 63) wsum[wid] = s;
  __syncthreads();
  if (wid == 0) {
    int ws = (lane < 16) ? wsum[lane] : 0;
    int inc = ws;
#pragma unroll
    for (int d = 1; d < 16; d <<= 1) {
      int u = __shfl_up(inc, d);
      if (lane >= d) inc += u;
    }
    if (lane < 16) wsum[lane] = inc - ws;  // exclusive wave offset
  }
  __syncthreads();
  int ex = wsum[wid] + s - mysum;  // exclusive prefix for this thread's first element
#pragma unroll
  for (int i = 0; i < 12; ++i) {
    int4 w;
    w.x = ex; ex += v[i].x;
    w.y = ex; ex += v[i].y;
    w.z = ex; ex += v[i].z;
    w.w = ex; ex += v[i].w;
    ((int4*)(a + t * 48))[i] = w;
  }
  if (blockIdx.x == 0 && t == 0) row_start[NN] = NE;
}

// ---------------- P1c: scatter records into per-(bucket,block) segments (LDS counters only) ----------------
__global__ __launch_bounds__(256) void k_p1c(const int* __restrict__ src,
                                             const int* __restrict__ dst,
                                             const int* __restrict__ ghd,
                                             const int* __restrict__ ghs,
                                             uint* __restrict__ rec_d,
                                             ushort* __restrict__ rec_s) {
  __shared__ int od[NBKT], os[NBKT];
  const int t = threadIdx.x;
  if (t < NBKT) {
    od[t] = ghd[t * P1B + blockIdx.x];
    os[t] = ghs[t * P1B + blockIdx.x];
  }
  __syncthreads();
  const int base = blockIdx.x * EPB;
#pragma unroll
  for (int i = 0; i < EPB / 256; ++i) {
    int e = base + i * 256 + t;
    int s = src[e], d = dst[e];
    int p = atomicAdd(&od[d >> BSH], 1);
    rec_d[p] = ((uint)s << BSH) | (uint)(d & 511);
    int q = atomicAdd(&os[s >> BSH], 1);
    rec_s[q] = (ushort)(s & 511);
  }
}

// ---------------- P2: per-bucket CSR build (row_start + edge_src) then out-degree -> ns ----------------
__global__ __launch_bounds__(256) void k_p2(const int* __restrict__ ghd,
                                            const int* __restrict__ ghs,
                                            const uint* __restrict__ rec_d,
                                            const ushort* __restrict__ rec_s,
                                            int* __restrict__ edge_src,
                                            int* __restrict__ row_start,
                                            float* __restrict__ ns) {
  __shared__ int lh[512];
  __shared__ int sc[256];
  const int k = blockIdx.x, t = threadIdx.x;
  // ---- phase 1: dst CSR ----
  {
    const int base = ghd[k * P1B];
    const int end = (k == NBKT - 1) ? NE : ghd[(k + 1) * P1B];
    lh[t] = 0; lh[t + 256] = 0;
    __syncthreads();
    for (int j = base + t; j < end; j += 256) atomicAdd(&lh[rec_d[j] & 511], 1);
    __syncthreads();
    int a0 = lh[2 * t], a1 = lh[2 * t + 1];
    sc[t] = a0 + a1;
    __syncthreads();
    for (int off = 1; off < 256; off <<= 1) {
      int add = (t >= off) ? sc[t - off] : 0;
      __syncthreads();
      sc[t] += add;
      __syncthreads();
    }
    int ex = t ? sc[t - 1] : 0;
    int e0 = ex, e1 = ex + a0;
    int n0 = k * 512 + 2 * t;
    if (n0 < NN) row_start[n0] = base + e0;
    if (n0 + 1 < NN) row_start[n0 + 1] = base + e1;
    __syncthreads();
    lh[2 * t] = base + e0;
    lh[2 * t + 1] = base + e1;
    __syncthreads();
    for (int j = base + t; j < end; j += 256) {
      uint r = rec_d[j];
      int p = atomicAdd(&lh[r & 511], 1);
      edge_src[p] = (int)(r >> BSH);
    }
  }
  __syncthreads();
  // ---- phase 2: src degree -> ns ----
  {
    const int base = ghs[k * P1B];
    const int end = (k == NBKT - 1) ? NE : ghs[(k + 1) * P1B];
    lh[t] = 0; lh[t + 256] = 0;
    __syncthreads();
    for (int j = base + t; j < end; j += 256) atomicAdd(&lh[rec_s[j]], 1);
    __syncthreads();
    int n0 = k * 512 + t, n1 = n0 + 256;
    if (n0 < NN) { int c = lh[t];       ns[n0] = rsqrtf((float)(c > 1 ? c : 1)); }
    if (n1 < NN) { int c = lh[t + 256]; ns[n1] = rsqrtf((float)(c > 1 ? c : 1)); }
  }
}

// ---------------- MFMA GEMM: h = feat @ W (bf16 out), B-in-registers, pipelined A stream ----------------
// Wave = 32 rows x 64 cols. Block = 4 waves = 64 rows x 128 cols.
__global__ __launch_bounds__(256) void k_gemm(const float* __restrict__ feat,
                                              const __bf16* __restrict__ Wt,
                                              __bf16* __restrict__ h) {
  const int w = threadIdx.x >> 6, l = threadIdx.x & 63;
  const int lr = l & 15, lg = l >> 4;
  const int row0 = blockIdx.x * 64 + (w >> 1) * 32;
  const int col0 = (w & 1) * 64;

  // ---- B fragments: 4 nf x 8 kk, loaded once (Wt is L2-hot, 64 KB) ----
  bf16x8 bf[4][8];
  const __bf16* bp = Wt + (size_t)(col0 + lr) * INF + lg * 8;
#pragma unroll
  for (int nf = 0; nf < 4; ++nf)
#pragma unroll
    for (int kk = 0; kk < 8; ++kk)
      bf[nf][kk] = *(const bf16x8*)(bp + (size_t)nf * 16 * INF + kk * 32);

  f32x4 acc[2][4];
#pragma unroll
  for (int i = 0; i < 2; ++i)
#pragma unroll
    for (int j = 0; j < 4; ++j) acc[i][j] = (f32x4)0.0f;

  // ---- A stream: rows mf*16 + lr, k-chunk lg*8, prefetch one kk ahead ----
  int r0 = row0 + lr;      if (r0 >= NN) r0 = NN - 1;
  int r1 = row0 + 16 + lr; if (r1 >= NN) r1 = NN - 1;
  const float* ap0 = feat + (size_t)r0 * INF + lg * 8;
  const float* ap1 = feat + (size_t)r1 * INF + lg * 8;

  float4 c0l = *(const float4*)(ap0);
  float4 c0h = *(const float4*)(ap0 + 4);
  float4 c1l = *(const float4*)(ap1);
  float4 c1h = *(const float4*)(ap1 + 4);

#pragma unroll
  for (int kk = 0; kk < 8; ++kk) {
    float4 n0l, n0h, n1l, n1h;
    if (kk < 7) {
      const float* p0 = ap0 + (kk + 1) * 32;
      const float* p1 = ap1 + (kk + 1) * 32;
      n0l = *(const float4*)(p0);
      n0h = *(const float4*)(p0 + 4);
      n1l = *(const float4*)(p1);
      n1h = *(const float4*)(p1 + 4);
    }
    bf16x8 a0, a1;
    a0[0] = (__bf16)c0l.x; a0[1] = (__bf16)c0l.y; a0[2] = (__bf16)c0l.z; a0[3] = (__bf16)c0l.w;
    a0[4] = (__bf16)c0h.x; a0[5] = (__bf16)c0h.y; a0[6] = (__bf16)c0h.z; a0[7] = (__bf16)c0h.w;
    a1[0] = (__bf16)c1l.x; a1[1] = (__bf16)c1l.y; a1[2] = (__bf16)c1l.z; a1[3] = (__bf16)c1l.w;
    a1[4] = (__bf16)c1h.x; a1[5] = (__bf16)c1h.y; a1[6] = (__bf16)c1h.z; a1[7] = (__bf16)c1h.w;
#pragma unroll
    for (int nf = 0; nf < 4; ++nf) {
      acc[0][nf] = __builtin_amdgcn_mfma_f32_16x16x32_bf16(a0, bf[nf][kk], acc[0][nf], 0, 0, 0);
      acc[1][nf] = __builtin_amdgcn_mfma_f32_16x16x32_bf16(a1, bf[nf][kk], acc[1][nf], 0, 0, 0);
    }
    c0l = n0l; c0h = n0h; c1l = n1l; c1h = n1h;
  }

  // ---- store: row = row0 + mf*16 + lg*4 + r, col = col0 + nf*16 + lr ----
#pragma unroll
  for (int mf = 0; mf < 2; ++mf) {
#pragma unroll
    for (int r = 0; r < 4; ++r) {
      int row = row0 + mf * 16 + lg * 4 + r;
      if (row < NN) {
        __bf16* hp = h + (size_t)row * OUTF + col0 + lr;
#pragma unroll
        for (int nf = 0; nf < 4; ++nf)
          hp[nf * 16] = (__bf16)(acc[mf][nf][r]);
      }
    }
  }
}

// ---------------- aggregation: out[n] = nd[n] * (sum ns[s]*h[s]) + b ----------------
// quarter-wave per edge: 16 lanes x uint4 = 256B row; 4 edges in flight, unroll 4.
__global__ __launch_bounds__(256) void k_aggr(const uint4* __restrict__ h4,
                                              const int* __restrict__ row_start,
                                              const float* __restrict__ ns,
                                              const int* __restrict__ edge_src,
                                              const float* __restrict__ bias,
                                              float* __restrict__ out) {
  const int wave = threadIdx.x >> 6;
  const int lane = threadIdx.x & 63;
  const int q = lane >> 4;    // quarter 0..3
  const int cl = lane & 15;   // 16B chunk within row
  const int n = blockIdx.x * 4 + wave;  // grid = NN/4 exact
  const int s0 = row_start[n];
  const int s1 = row_start[n + 1];
  const int cnt = s1 - s0;

  float a0 = 0.f, a1 = 0.f, a2 = 0.f, a3 = 0.f, a4 = 0.f, a5 = 0.f, a6 = 0.f, a7 = 0.f;
  for (int j0 = 0; j0 < cnt; j0 += 64) {
    int nb = cnt - j0; if (nb > 64) nb = 64;
    int idv = 0; float nsv = 0.f;
    if (lane < nb) idv = edge_src[s0 + j0 + lane];
    if (lane < nb) nsv = ns[idv];
#pragma unroll 4
    for (int j = 0; j < nb; j += 4) {
      int jj = j + q;
      int e = __shfl(idv, jj);
      float w = __shfl(nsv, jj);
      if (jj < nb) {
        uint4 v = h4[(size_t)e * 16 + cl];
        a0 += w * bflo(v.x); a1 += w * bfhi(v.x);
        a2 += w * bflo(v.y); a3 += w * bfhi(v.y);
        a4 += w * bflo(v.z); a5 += w * bfhi(v.z);
        a6 += w * bflo(v.w); a7 += w * bfhi(v.w);
      }
    }
  }
  a0 += __shfl_xor(a0, 16); a1 += __shfl_xor(a1, 16); a2 += __shfl_xor(a2, 16); a3 += __shfl_xor(a3, 16);
  a4 += __shfl_xor(a4, 16); a5 += __shfl_xor(a5, 16); a6 += __shfl_xor(a6, 16); a7 += __shfl_xor(a7, 16);
  a0 += __shfl_xor(a0, 32); a1 += __shfl_xor(a1, 32); a2 += __shfl_xor(a2, 32); a3 += __shfl_xor(a3, 32);
  a4 += __shfl_xor(a4, 32); a5 += __shfl_xor(a5, 32); a6 += __shfl_xor(a6, 32); a7 += __shfl_xor(a7, 32);

  if (q == 0) {
    float ndv = rsqrtf((float)(cnt > 1 ? cnt : 1));
    const float4* b4 = (const float4*)bias;
    float4 ba = b4[2 * cl], bb = b4[2 * cl + 1];
    float4 o0, o1;
    o0.x = a0 * ndv + ba.x; o0.y = a1 * ndv + ba.y; o0.z = a2 * ndv + ba.z; o0.w = a3 * ndv + ba.w;
    o1.x = a4 * ndv + bb.x; o1.y = a5 * ndv + bb.y; o1.z = a6 * ndv + bb.z; o1.w = a7 * ndv + bb.w;
    float4* op = (float4*)(out + (size_t)n * OUTF);
    op[2 * cl] = o0;
    op[2 * cl + 1] = o1;
  }
}

// ---------------- launch ----------------
extern "C" void kernel_launch(void* const* d_in, const int* in_sizes, int n_in,
                              void* d_out, int out_size, void* d_ws, size_t ws_size,
                              hipStream_t stream) {
  const float* feat = (const float*)d_in[0];
  const int* src = (const int*)d_in[1];
  const int* dst = (const int*)d_in[2];
  const float* Wm = (const float*)d_in[3];
  const float* bias = (const float*)d_in[4];
  float* out = (float*)d_out;

  char* ws = (char*)d_ws;
  __bf16* h        = (__bf16*)(ws + 0);            // 25,600,000
  __bf16* Wt       = (__bf16*)(ws + 25600000);     //     65,536
  int*    ghd      = (int*)(ws + 25665536);        //    196,608 (padded)
  int*    ghs      = (int*)(ws + 25862144);        //    196,608 (padded)
  uint*   rec_d    = (uint*)(ws + 26058752);       //  6,400,000
  ushort* rec_s    = (ushort*)(ws + 32458752);     //  3,200,000
  int*    edge_src = (int*)(ws + 35658752);        //  6,400,000
  int*    row_start= (int*)(ws + 42058752);        //    400,016
  float*  ns       = (float*)(ws + 42458768);      //    400,000

  k_p1a<<<P1B + 128, 256, 0, stream>>>(src, dst, ghd, ghs, Wm, Wt);
  k_p1b<<<2, 1024, 0, stream>>>(ghd, ghs, row_start);
  k_p1c<<<P1B, 256, 0, stream>>>(src, dst, ghd, ghs, rec_d, rec_s);
  k_p2<<<NBKT, 256, 0, stream>>>(ghd, ghs, rec_d, rec_s, edge_src, row_start, ns);
  k_gemm<<<(NN + 63) / 64, 256, 0, stream>>>(feat, Wt, h);
  k_aggr<<<NN / 4, 256, 0, stream>>>((const uint4*)h, row_start, ns, edge_src, bias, out);
}